// Round 5
// baseline (146.412 us; speedup 1.0000x reference)
//
#include <hip/hip_runtime.h>
#include <hip/hip_bf16.h>

// ============================================================================
// indices ∈ [0,64) => backbone + theta have only 64 distinct rows. Compute
// per-class (7 MB, L2-resident), bucket batches by class, run only the tiny
// per-batch MLPs with class-shared weights.
// R5: func v5 — register tile 4 batches x 2 cols per thread so each LDS
// weight read (b64 multicast, 4-8 distinct addrs/wave) feeds 8 FMAs; cuts
// LDS-issue 3-4x (v4 was broadcast-instruction bound). Backbone fc1: float4
// out-tile, 16-way K-split -> 64-deep load chain (was 256).
// ============================================================================

#define LEAKY 0.2f
#define NCLS 64
#define B_TOT 8192
#define NSLICE 4
#define ESTRIDE 68   // odd f4 stride -> conflict-free e-act rows
#define FSTRIDE 132  // odd f4 stride -> conflict-free f-act rows

// theta_e (per class, 5456 fl): W1e[0,128) b1e[128,192) W2e[192,4288)
//   b2e[4288,4352) W3e[4352,5376) b3e[5376,5392)
// theta_f (per class, 21768 fl): W1f[0,4096) b1f[4096,4224) W2f[4224,20608)
//   b2f[20608,20736) W3f[20736,21760) b3f[21760,21768)

__device__ __forceinline__ float lrelu(float x) { return x >= 0.f ? x : LEAKY * x; }

// ---------------------------------------------------------------------------
// K1: blocks 0..63: fused backbone for class c. block 64: bucket. 1024 thr.
// ---------------------------------------------------------------------------
__global__ __launch_bounds__(1024) void backbone_bucket_kernel(
    const float* __restrict__ maps,
    const float* __restrict__ fc1_w, const float* __restrict__ fc1_b,
    const float* __restrict__ fc2_w, const float* __restrict__ fc2_b,
    const float* __restrict__ fc3_w, const float* __restrict__ fc3_b,
    const float* __restrict__ bn_w,  const float* __restrict__ bn_b,
    float* __restrict__ z,
    const int* __restrict__ idx, int* __restrict__ counts,
    int* __restrict__ offsets, int* __restrict__ perm)
{
    __shared__ float m[1024];
    __shared__ __align__(16) float4 red4[1024];
    __shared__ __align__(16) float h1[256];
    __shared__ __align__(16) float h2[128];
    __shared__ __align__(16) float h3[128];
    __shared__ int cnt[16][64];
    __shared__ int wcur[16][64];

    const int t = threadIdx.x;

    if (blockIdx.x == 64) {
        // ---------------- bucket ----------------
        const int w = t >> 6;
        cnt[w][t & 63] = 0;
        __syncthreads();
        int my[8];
#pragma unroll
        for (int r = 0; r < 8; ++r) {
            my[r] = idx[r * 1024 + t];
            atomicAdd(&cnt[w][my[r]], 1);
        }
        __syncthreads();
        if (t < 64) {
            int run = 0;
#pragma unroll
            for (int w2 = 0; w2 < 16; ++w2) {
                const int v = cnt[w2][t];
                wcur[w2][t] = run;
                run += v;
            }
            counts[t] = run;
            int x = run;
            for (int d = 1; d < 64; d <<= 1) {
                const int y = __shfl_up(x, d, 64);
                if (t >= d) x += y;
            }
            const int basec = x - run;
            offsets[t] = basec;
#pragma unroll
            for (int w2 = 0; w2 < 16; ++w2) wcur[w2][t] += basec;
        }
        __syncthreads();
#pragma unroll
        for (int r = 0; r < 8; ++r) {
            const int p = atomicAdd(&wcur[w][my[r]], 1);
            perm[p] = r * 1024 + t;
        }
        return;
    }

    // ---------------- backbone for class c ----------------
    const int c = blockIdx.x;
    m[t] = maps[(size_t)c * 1024 + t];
    __syncthreads();

    // fc1: 1024 -> 256 (leaky); thread = 4-out group (t&63) x kslice (t>>6, 64k)
    {
        const int og = t & 63, ks = t >> 6;
        const float* wp = fc1_w + og * 4;
        float4 acc = {0.f, 0.f, 0.f, 0.f};
#pragma unroll 8
        for (int i = 0; i < 64; ++i) {
            const int k = ks * 64 + i;
            const float mk = m[k];
            const float4 w = *(const float4*)&wp[(size_t)k * 256];
            acc.x += mk * w.x; acc.y += mk * w.y;
            acc.z += mk * w.z; acc.w += mk * w.w;
        }
        red4[t] = acc;
    }
    __syncthreads();
    if (t < 64) {
        float4 a = *(const float4*)&fc1_b[t * 4];
#pragma unroll
        for (int r = 0; r < 16; ++r) {
            const float4 v = red4[r * 64 + t];
            a.x += v.x; a.y += v.y; a.z += v.z; a.w += v.w;
        }
        a.x = lrelu(a.x); a.y = lrelu(a.y); a.z = lrelu(a.z); a.w = lrelu(a.w);
        *(float4*)&h1[t * 4] = a;
    }
    __syncthreads();
    // fc2: 256 -> 128 (leaky); 32 out-groups x 32 kslices of 8
    {
        const int og = t & 31, ks = t >> 5;
        float4 acc = {0.f, 0.f, 0.f, 0.f};
#pragma unroll
        for (int i = 0; i < 8; ++i) {
            const int k = ks * 8 + i;
            const float hk = h1[k];
            const float4 w = *(const float4*)&fc2_w[k * 128 + og * 4];
            acc.x += hk * w.x; acc.y += hk * w.y;
            acc.z += hk * w.z; acc.w += hk * w.w;
        }
        red4[t] = acc;
    }
    __syncthreads();
    if (t < 32) {
        float4 a = *(const float4*)&fc2_b[t * 4];
#pragma unroll
        for (int r = 0; r < 32; ++r) {
            const float4 v = red4[r * 32 + t];
            a.x += v.x; a.y += v.y; a.z += v.z; a.w += v.w;
        }
        a.x = lrelu(a.x); a.y = lrelu(a.y); a.z = lrelu(a.z); a.w = lrelu(a.w);
        *(float4*)&h2[t * 4] = a;
    }
    __syncthreads();
    // fc3: 128 -> 128 (leaky); 32 out-groups x 32 kslices of 4
    {
        const int og = t & 31, ks = t >> 5;
        float4 acc = {0.f, 0.f, 0.f, 0.f};
#pragma unroll
        for (int i = 0; i < 4; ++i) {
            const int k = ks * 4 + i;
            const float hk = h2[k];
            const float4 w = *(const float4*)&fc3_w[k * 128 + og * 4];
            acc.x += hk * w.x; acc.y += hk * w.y;
            acc.z += hk * w.z; acc.w += hk * w.w;
        }
        red4[t] = acc;
    }
    __syncthreads();
    if (t < 32) {
        float4 a = *(const float4*)&fc3_b[t * 4];
#pragma unroll
        for (int r = 0; r < 32; ++r) {
            const float4 v = red4[r * 32 + t];
            a.x += v.x; a.y += v.y; a.z += v.z; a.w += v.w;
        }
        a.x = lrelu(a.x); a.y = lrelu(a.y); a.z = lrelu(a.z); a.w = lrelu(a.w);
        *(float4*)&h3[t * 4] = a;
    }
    __syncthreads();
    // bn: 128 -> 32 (no act); 8 out-groups x 128 kslices of 1
    {
        const int og = t & 7, ks = t >> 3;
        const float hk = h3[ks];
        const float4 w = *(const float4*)&bn_w[ks * 32 + og * 4];
        float4 acc;
        acc.x = hk * w.x; acc.y = hk * w.y; acc.z = hk * w.z; acc.w = hk * w.w;
        red4[t] = acc;
    }
    __syncthreads();
    if (t < 8) {
        float4 a = *(const float4*)&bn_b[t * 4];
#pragma unroll
        for (int r = 0; r < 128; ++r) {
            const float4 v = red4[r * 8 + t];
            a.x += v.x; a.y += v.y; a.z += v.z; a.w += v.w;
        }
        *(float4*)&z[c * 32 + t * 4] = a;
    }
}

// ---------------------------------------------------------------------------
// K2: theta, grid (107, 8): block owns 256 cols x 8 classes. Weights in regs.
// ---------------------------------------------------------------------------
__global__ __launch_bounds__(256) void theta_kernel(
    const float* __restrict__ z,
    const float* __restrict__ e_w, const float* __restrict__ e_b,
    const float* __restrict__ f_w, const float* __restrict__ f_b,
    float* __restrict__ th_e, float* __restrict__ th_f)
{
    __shared__ __align__(16) float zl[2048];
    const int t = threadIdx.x;
    ((float4*)zl)[t]       = ((const float4*)z)[t];
    ((float4*)zl)[t + 256] = ((const float4*)z)[t + 256];
    __syncthreads();

    int j = blockIdx.x * 256 + t;
    const int cbase = blockIdx.y * 8;
    const float* wbase;
    float* op;
    int stride;
    float bias;
    if (j < 5456) {
        wbase = e_w + j; bias = e_b[j]; op = th_e + j; stride = 5456;
    } else {
        const int jj = j - 5456;
        if (jj >= 21768) return;
        wbase = f_w + jj; bias = f_b[jj]; op = th_f + jj; stride = 21768;
    }
    float wk[32];
#pragma unroll
    for (int k = 0; k < 32; ++k) wk[k] = wbase[(size_t)k * stride];

#pragma unroll
    for (int cc = 0; cc < 8; cc += 4) {
        const int c0 = cbase + cc;
        float a0 = bias, a1 = bias, a2 = bias, a3 = bias;
#pragma unroll
        for (int k4 = 0; k4 < 8; ++k4) {
            const float4 z0 = *(const float4*)&zl[(c0 + 0) * 32 + k4 * 4];
            const float4 z1 = *(const float4*)&zl[(c0 + 1) * 32 + k4 * 4];
            const float4 z2 = *(const float4*)&zl[(c0 + 2) * 32 + k4 * 4];
            const float4 z3 = *(const float4*)&zl[(c0 + 3) * 32 + k4 * 4];
            const float w0 = wk[k4 * 4], w1 = wk[k4 * 4 + 1];
            const float w2 = wk[k4 * 4 + 2], w3 = wk[k4 * 4 + 3];
            a0 += z0.x * w0 + z0.y * w1 + z0.z * w2 + z0.w * w3;
            a1 += z1.x * w0 + z1.y * w1 + z1.z * w2 + z1.w * w3;
            a2 += z2.x * w0 + z2.y * w1 + z2.z * w2 + z2.w * w3;
            a3 += z3.x * w0 + z3.y * w1 + z3.z * w2 + z3.w * w3;
        }
        op[(size_t)(c0 + 0) * stride] = a0;
        op[(size_t)(c0 + 1) * stride] = a1;
        op[(size_t)(c0 + 2) * stride] = a2;
        op[(size_t)(c0 + 3) * stride] = a3;
    }
}

// ---------------------------------------------------------------------------
// K3: func v5. grid (64, 4), 512 thr. 32 batches/pass. Register tile:
// 4 batches x 2 cols per thread -> weight reads feed 8 FMAs.
//   e view: vbs = t&15 (vbatches vbs+16j, j<4), ecp = t>>4 (cols 2ecp,2ecp+1)
//   f view: fbs = t&7  (batches  fbs+8j,  j<4), fcp = t>>3 (cols 2fcp,2fcp+1)
// ---------------------------------------------------------------------------
__global__ __launch_bounds__(512) void func_kernel(
    const float* __restrict__ states,
    const float* __restrict__ th_e_all, const float* __restrict__ th_f_all,
    const int* __restrict__ counts, const int* __restrict__ offsets,
    const int* __restrict__ perm, float* __restrict__ out)
{
    __shared__ __align__(16) float wbuf[5392];   // e-block / f-L1 / W2f quarter
    __shared__ __align__(16) float w3fb[1160];   // b2f | W3f | b3f (persistent)
    __shared__ __align__(16) float actA[4352];
    __shared__ __align__(16) float actB[4352];
    __shared__ __align__(16) float part[512];

    const int c = blockIdx.x;
    const int s = blockIdx.y;
    const int nb   = counts[c];
    const int base = offsets[c];
    const int chunk = (nb + NSLICE - 1) / NSLICE;
    const int k0 = s * chunk;
    const int k1 = (nb < k0 + chunk) ? nb : (k0 + chunk);
    const int cnt = (k1 > k0) ? (k1 - k0) : 0;
    if (cnt == 0) return;

    const float* te = th_e_all + (size_t)c * 5456;
    const float* tf = th_f_all + (size_t)c * 21768;

    const int t   = threadIdx.x;
    const int vbs = t & 15;
    const int ce  = (t >> 4) * 2;   // e col pair base (< 64)
    const int fbs = t & 7;
    const int cf  = (t >> 3) * 2;   // f col pair base (< 128)

    for (int j = t * 4; j < 1160; j += 2048)
        *(float4*)&w3fb[j] = *(const float4*)&tf[20608 + j];
    for (int j = t * 4; j < 5392; j += 2048)
        *(float4*)&wbuf[j] = *(const float4*)&te[j];

    const int passes = (cnt + 31) >> 5;
    for (int p = 0; p < passes; ++p) {
        __syncthreads();   // staging visible / prev-pass act+part reads done
        if (p) {
            for (int j = t * 4; j < 5392; j += 2048)
                *(float4*)&wbuf[j] = *(const float4*)&te[j];
            __syncthreads();
        }

        // states for this thread's two e-batches (vbs, vbs+16)
        const int kkA = k0 + p * 32 + vbs;
        const int kkB = kkA + 16;
        const int biA = (kkA < k1) ? perm[base + kkA] : 0;
        const int biB = (kkB < k1) ? perm[base + kkB] : 0;
        const float4 stA = *(const float4*)&states[(size_t)biA * 4];
        const float4 stB = *(const float4*)&states[(size_t)biB * 4];
        // vb = vbs+16j: j=0 (bA,S), j=1 (bB,S), j=2 (bA,G), j=3 (bB,G)
        const float i0[4] = {stA.x, stB.x, stA.z, stB.z};
        const float i1[4] = {stA.y, stB.y, stA.w, stB.w};

        // ---- e-L1: 2 -> 64 (leaky) ----
        {
            const float2 wa = *(const float2*)&wbuf[ce];
            const float2 wb = *(const float2*)&wbuf[64 + ce];
            const float2 bb = *(const float2*)&wbuf[128 + ce];
#pragma unroll
            for (int j = 0; j < 4; ++j) {
                float2 o;
                o.x = lrelu(i0[j] * wa.x + i1[j] * wb.x + bb.x);
                o.y = lrelu(i0[j] * wa.y + i1[j] * wb.y + bb.y);
                *(float2*)&actA[(vbs + 16 * j) * ESTRIDE + ce] = o;
            }
        }
        __syncthreads();

        // ---- e-L2: 64 -> 64 (leaky) ----
        {
            float a0[4] = {0, 0, 0, 0}, a1[4] = {0, 0, 0, 0};
#pragma unroll 4
            for (int k4 = 0; k4 < 16; ++k4) {
                float4 y[4];
#pragma unroll
                for (int j = 0; j < 4; ++j)
                    y[j] = *(const float4*)&actA[(vbs + 16 * j) * ESTRIDE + k4 * 4];
#pragma unroll
                for (int u = 0; u < 4; ++u) {
                    const float2 w = *(const float2*)&wbuf[192 + (k4 * 4 + u) * 64 + ce];
#pragma unroll
                    for (int j = 0; j < 4; ++j) {
                        const float yv = (&y[j].x)[u];
                        a0[j] += yv * w.x;
                        a1[j] += yv * w.y;
                    }
                }
            }
            const float2 b2 = *(const float2*)&wbuf[4288 + ce];
#pragma unroll
            for (int j = 0; j < 4; ++j) {
                float2 o;
                o.x = lrelu(a0[j] + b2.x);
                o.y = lrelu(a1[j] + b2.y);
                *(float2*)&actB[(vbs + 16 * j) * ESTRIDE + ce] = o;
            }
        }
        __syncthreads();

        // ---- e-L3: 64 -> 16 (no act) -> zf into actA (f layout) ----
        if (t < 256) {
            const int c3 = t >> 4;   // 16 cols
            float a[4] = {0, 0, 0, 0};
#pragma unroll 4
            for (int k4 = 0; k4 < 16; ++k4) {
                float4 y[4];
#pragma unroll
                for (int j = 0; j < 4; ++j)
                    y[j] = *(const float4*)&actB[(vbs + 16 * j) * ESTRIDE + k4 * 4];
#pragma unroll
                for (int u = 0; u < 4; ++u) {
                    const float w = wbuf[4352 + (k4 * 4 + u) * 16 + c3];
#pragma unroll
                    for (int j = 0; j < 4; ++j) a[j] += (&y[j].x)[u] * w;
                }
            }
            const float b3 = wbuf[5376 + c3];
#pragma unroll
            for (int j = 0; j < 4; ++j) {
                const int vb = vbs + 16 * j;
                actA[(vb & 31) * FSTRIDE + (vb >> 5) * 16 + c3] = a[j] + b3;
            }
        }
        __syncthreads();

        // ---- stage f-L1 weights ----
        for (int j = t * 4; j < 4224; j += 2048)
            *(float4*)&wbuf[j] = *(const float4*)&tf[j];
        __syncthreads();

        // ---- f-L1: 32 -> 128 (leaky) ----
        {
            float a0[4] = {0, 0, 0, 0}, a1[4] = {0, 0, 0, 0};
#pragma unroll
            for (int k4 = 0; k4 < 8; ++k4) {
                float4 y[4];
#pragma unroll
                for (int j = 0; j < 4; ++j)
                    y[j] = *(const float4*)&actA[(fbs + 8 * j) * FSTRIDE + k4 * 4];
#pragma unroll
                for (int u = 0; u < 4; ++u) {
                    const float2 w = *(const float2*)&wbuf[(k4 * 4 + u) * 128 + cf];
#pragma unroll
                    for (int j = 0; j < 4; ++j) {
                        const float yv = (&y[j].x)[u];
                        a0[j] += yv * w.x;
                        a1[j] += yv * w.y;
                    }
                }
            }
            const float2 b1 = *(const float2*)&wbuf[4096 + cf];
#pragma unroll
            for (int j = 0; j < 4; ++j) {
                float2 o;
                o.x = lrelu(a0[j] + b1.x);
                o.y = lrelu(a1[j] + b1.y);
                *(float2*)&actB[(fbs + 8 * j) * FSTRIDE + cf] = o;
            }
        }
        __syncthreads();

        // ---- f-L2: 128 -> 128 (leaky), W2f in 4 staged K-quarters ----
        {
            float a0[4] = {0, 0, 0, 0}, a1[4] = {0, 0, 0, 0};
#pragma unroll
            for (int h = 0; h < 4; ++h) {
                if (h) __syncthreads();
                for (int j = t * 4; j < 4096; j += 2048)
                    *(float4*)&wbuf[j] = *(const float4*)&tf[4224 + h * 4096 + j];
                __syncthreads();
#pragma unroll 4
                for (int k4 = 0; k4 < 8; ++k4) {
                    float4 y[4];
#pragma unroll
                    for (int j = 0; j < 4; ++j)
                        y[j] = *(const float4*)&actB[(fbs + 8 * j) * FSTRIDE + h * 32 + k4 * 4];
#pragma unroll
                    for (int u = 0; u < 4; ++u) {
                        const float2 w = *(const float2*)&wbuf[(k4 * 4 + u) * 128 + cf];
#pragma unroll
                        for (int j = 0; j < 4; ++j) {
                            const float yv = (&y[j].x)[u];
                            a0[j] += yv * w.x;
                            a1[j] += yv * w.y;
                        }
                    }
                }
            }
            const float2 b2 = *(const float2*)&w3fb[cf];
#pragma unroll
            for (int j = 0; j < 4; ++j) {
                float2 o;
                o.x = lrelu(a0[j] + b2.x);
                o.y = lrelu(a1[j] + b2.y);
                *(float2*)&actA[(fbs + 8 * j) * FSTRIDE + cf] = o;
            }
        }
        __syncthreads();

        // ---- f-L3: 128 -> 8 (no act), K-halved, then sin/cos ----
        {
            const int bat = t & 31, c8 = (t >> 5) & 7, kh = t >> 8;
            float a = 0.f;
#pragma unroll 4
            for (int k4 = kh * 16; k4 < kh * 16 + 16; ++k4) {
                const float4 y = *(const float4*)&actA[bat * FSTRIDE + k4 * 4];
#pragma unroll
                for (int u = 0; u < 4; ++u)
                    a += (&y.x)[u] * w3fb[128 + (k4 * 4 + u) * 8 + c8];
            }
            part[kh * 256 + bat * 8 + c8] = a;
        }
        __syncthreads();
        if (t < 256) {
            const int bat = t & 31, c8 = t >> 5;
            const int kk = k0 + p * 32 + bat;
            if (kk < k1) {
                const int bi = perm[base + kk];
                const float a = part[bat * 8 + c8] + part[256 + bat * 8 + c8]
                              + w3fb[1152 + c8];
                out[(size_t)bi * 16 + c8]     = __sinf(a);
                out[(size_t)bi * 16 + 8 + c8] = __cosf(a);
            }
        }
    }
}

// ---------------------------------------------------------------------------
extern "C" void kernel_launch(void* const* d_in, const int* in_sizes, int n_in,
                              void* d_out, int out_size, void* d_ws, size_t ws_size,
                              hipStream_t stream)
{
    const int*   indices = (const int*)  d_in[0];
    const float* states  = (const float*)d_in[1];
    const float* maps    = (const float*)d_in[2];
    const float* fc1_w   = (const float*)d_in[3];
    const float* fc1_b   = (const float*)d_in[4];
    const float* fc2_w   = (const float*)d_in[5];
    const float* fc2_b   = (const float*)d_in[6];
    const float* fc3_w   = (const float*)d_in[7];
    const float* fc3_b   = (const float*)d_in[8];
    const float* bn_w    = (const float*)d_in[9];
    const float* bn_b    = (const float*)d_in[10];
    const float* e_w     = (const float*)d_in[11];
    const float* e_b     = (const float*)d_in[12];
    const float* f_w     = (const float*)d_in[13];
    const float* f_b     = (const float*)d_in[14];
    float* out = (float*)d_out;

    float* ws   = (float*)d_ws;
    float* z    = ws;                    // 2048
    float* th_e = ws + 2048;             // 349184
    float* th_f = ws + 351232;           // 1393152
    int* counts  = (int*)(ws + 1744384); // 64
    int* offsets = counts + 64;          // 64
    int* perm    = counts + 128;         // 8192

    backbone_bucket_kernel<<<65, 1024, 0, stream>>>(
        maps, fc1_w, fc1_b, fc2_w, fc2_b, fc3_w, fc3_b, bn_w, bn_b, z,
        indices, counts, offsets, perm);
    theta_kernel<<<dim3(107, 8), 256, 0, stream>>>(
        z, e_w, e_b, f_w, f_b, th_e, th_f);
    func_kernel<<<dim3(NCLS, NSLICE), 512, 0, stream>>>(
        states, th_e, th_f, counts, offsets, perm, out);
}